// Round 3
// baseline (1196.978 us; speedup 1.0000x reference)
//
#include <hip/hip_runtime.h>
#include <hip/hip_cooperative_groups.h>
#include <stdint.h>

namespace cg = cooperative_groups;
typedef float f4 __attribute__((ext_vector_type(4)));

// ---------------------------------------------------------------------------
// Cooperative pipelined kernel. F frames in NC=4 chunks of CF=64.
// Block b: quarter q = b&3, frame-slot fo = b>>2. Per iteration it:
//   [it>0]  select + gather chunk it-1  (x re-reads are L3-resident)
//   [it<NC] score quarter of chunk it   (830MB/NC HBM stream)
//   [it<NC] grid.sync()
// Selection: rank-select (value desc, index asc) == stable argsort(-softmax)
// top-K (softmax is monotonic -> skipped); f64 throughout, bitwise identical
// ordering to the previously-passing kernel.
// ---------------------------------------------------------------------------
__global__ __launch_bounds__(1024)
void pipe_kernel(const float* __restrict__ x,
                 const float* __restrict__ pre_w,
                 const float* __restrict__ pre_b,
                 const float* __restrict__ W,
                 const float* __restrict__ bias,
                 float* __restrict__ out,
                 double* __restrict__ s_glob,
                 int T, int D, int K, int F, int NC) {
    cg::grid_group grid = cg::this_grid();
    __shared__ double   s_sh[576];
    __shared__ double   lg[576];
    __shared__ unsigned flags[32];
    __shared__ int      sel[256];

    const int q    = blockIdx.x & 3;
    const int fo   = blockIdx.x >> 2;
    const int CF   = F / NC;
    const int tid  = threadIdx.x;
    const int wave = tid >> 6;
    const int lane = tid & 63;
    const int n4   = D >> 2;
    const int TQ   = T >> 2;   // tokens per quarter (144)
    const int KQ   = K >> 2;   // gather rows per quarter (36)

    for (int it = 0; it <= NC; ++it) {
        // ---------- select + gather for chunk it-1 ----------
        if (it > 0) {
            const int fB = (it - 1) * CF + fo;
            for (int t = tid; t < T; t += 1024) s_sh[t] = s_glob[(size_t)fB * T + t];
            if (tid < 32) flags[tid] = 0u;
            __syncthreads();

            // GEMV logits (redundant across the frame's 4 blocks; W is L2-hot)
            if (tid < T) {
                const float* Wc = W + tid;
                double a0 = 0, a1 = 0, a2 = 0, a3 = 0;
                int tp = 0;
                for (; tp + 4 <= T; tp += 4) {
                    a0 += s_sh[tp + 0] * (double)Wc[(size_t)(tp + 0) * T];
                    a1 += s_sh[tp + 1] * (double)Wc[(size_t)(tp + 1) * T];
                    a2 += s_sh[tp + 2] * (double)Wc[(size_t)(tp + 2) * T];
                    a3 += s_sh[tp + 3] * (double)Wc[(size_t)(tp + 3) * T];
                }
                for (; tp < T; ++tp) a0 += s_sh[tp] * (double)Wc[(size_t)tp * T];
                lg[tid] = ((a0 + a1) + (a2 + a3)) + (double)bias[tid];
            }
            __syncthreads();

            // rank-select: rank < K  <=>  in stable top-K of argsort(-logits)
            if (tid < T) {
                const double v = lg[tid];
                int rank = 0;
                #pragma unroll 4
                for (int tp = 0; tp < T; ++tp) {
                    double u = lg[tp];
                    rank += (u > v) || (u == v && tp < tid);
                }
                if (rank < K) atomicOr(&flags[tid >> 5], 1u << (tid & 31));
            }
            __syncthreads();

            // compact selected tokens in ascending index order
            if (tid < T) {
                if ((flags[tid >> 5] >> (tid & 31)) & 1u) {
                    int pos = __popc(flags[tid >> 5] & ((1u << (tid & 31)) - 1u));
                    for (int u2 = 0; u2 < (tid >> 5); ++u2) pos += __popc(flags[u2]);
                    sel[pos] = tid;
                }
            }
            __syncthreads();

            // gather this block's quarter of the selected rows
            for (int j = wave; j < KQ; j += 16) {
                const int kk = q * KQ + j;
                const int t  = sel[kk];
                const f4* src = (const f4*)(x + ((size_t)fB * T + t) * D);
                f4*       dst = (f4*)(out + ((size_t)fB * K + kk) * D);
                for (int p = lane; p < n4; p += 64)
                    __builtin_nontemporal_store(src[p], &dst[p]);
            }
        }

        // ---------- score quarter of chunk it ----------
        if (it < NC) {
            const int fA = it * CF + fo;
            const double pb = (double)pre_b[0];
            const f4* wv = (const f4*)pre_w;
            const int nm = TQ >> 4;            // rows per wave (9)
            int m = 0;
            for (; m + 3 <= nm; m += 3) {      // 3 rows in flight per wave
                const int t0 = q * TQ + wave + 16 * m;
                const int t1 = t0 + 16, t2 = t0 + 32;
                const f4* r0 = (const f4*)(x + ((size_t)fA * T + t0) * D);
                const f4* r1 = (const f4*)(x + ((size_t)fA * T + t1) * D);
                const f4* r2 = (const f4*)(x + ((size_t)fA * T + t2) * D);
                double a0 = 0, a1 = 0, a2 = 0;
                for (int p = lane; p < n4; p += 64) {
                    f4 w4 = wv[p];
                    f4 v0 = r0[p], v1 = r1[p], v2 = r2[p];
                    a0 += (double)v0.x*(double)w4.x + (double)v0.y*(double)w4.y
                        + (double)v0.z*(double)w4.z + (double)v0.w*(double)w4.w;
                    a1 += (double)v1.x*(double)w4.x + (double)v1.y*(double)w4.y
                        + (double)v1.z*(double)w4.z + (double)v1.w*(double)w4.w;
                    a2 += (double)v2.x*(double)w4.x + (double)v2.y*(double)w4.y
                        + (double)v2.z*(double)w4.z + (double)v2.w*(double)w4.w;
                }
                #pragma unroll
                for (int off = 32; off > 0; off >>= 1) {
                    a0 += __shfl_down(a0, off);
                    a1 += __shfl_down(a1, off);
                    a2 += __shfl_down(a2, off);
                }
                if (lane == 0) {
                    s_glob[(size_t)fA * T + t0] = a0 + pb;
                    s_glob[(size_t)fA * T + t1] = a1 + pb;
                    s_glob[(size_t)fA * T + t2] = a2 + pb;
                }
            }
            for (; m < nm; ++m) {              // generic tail (unused for T=576)
                const int t0 = q * TQ + wave + 16 * m;
                const f4* r0 = (const f4*)(x + ((size_t)fA * T + t0) * D);
                double a0 = 0;
                for (int p = lane; p < n4; p += 64) {
                    f4 w4 = wv[p]; f4 v0 = r0[p];
                    a0 += (double)v0.x*(double)w4.x + (double)v0.y*(double)w4.y
                        + (double)v0.z*(double)w4.z + (double)v0.w*(double)w4.w;
                }
                #pragma unroll
                for (int off = 32; off > 0; off >>= 1) a0 += __shfl_down(a0, off);
                if (lane == 0) s_glob[(size_t)fA * T + t0] = a0 + pb;
            }
            __threadfence();
            grid.sync();
        }
    }
}

// ---------------------------------------------------------------------------
// Fallback (previous passing kernel): fused one-block-per-frame.
// ---------------------------------------------------------------------------
__global__ __launch_bounds__(1024)
void fused_select_kernel(const float* __restrict__ x,
                         const float* __restrict__ pre_w,
                         const float* __restrict__ pre_b,
                         const float* __restrict__ W,
                         const float* __restrict__ bias,
                         float* __restrict__ out,
                         int T, int D, int K) {
    __shared__ double   s_sh[1024];
    __shared__ double   lg[1024];
    __shared__ unsigned flags[32];
    __shared__ int      sel[576];

    const int f    = blockIdx.x;
    const int tid  = threadIdx.x;
    const int wave = tid >> 6;
    const int lane = tid & 63;
    const int nw   = blockDim.x >> 6;
    const int n4   = D >> 2;

    const f4* wv = (const f4*)pre_w;
    for (int t = wave; t < T; t += nw) {
        const f4* xr = (const f4*)(x + ((size_t)f * T + t) * D);
        double acc = 0.0;
        for (int p = lane; p < n4; p += 64) {
            f4 a = xr[p], c = wv[p];
            acc += (double)a.x * (double)c.x + (double)a.y * (double)c.y
                 + (double)a.z * (double)c.z + (double)a.w * (double)c.w;
        }
#pragma unroll
        for (int off = 32; off > 0; off >>= 1) acc += __shfl_down(acc, off);
        if (lane == 0) s_sh[t] = acc + (double)pre_b[0];
    }
    if (tid < 32) flags[tid] = 0u;
    __syncthreads();

    if (tid < T) {
        const float* Wc = W + tid;
        double a0 = 0, a1 = 0, a2 = 0, a3 = 0;
        int tp = 0;
        for (; tp + 4 <= T; tp += 4) {
            a0 += s_sh[tp + 0] * (double)Wc[(size_t)(tp + 0) * T];
            a1 += s_sh[tp + 1] * (double)Wc[(size_t)(tp + 1) * T];
            a2 += s_sh[tp + 2] * (double)Wc[(size_t)(tp + 2) * T];
            a3 += s_sh[tp + 3] * (double)Wc[(size_t)(tp + 3) * T];
        }
        for (; tp < T; ++tp) a0 += s_sh[tp] * (double)Wc[(size_t)tp * T];
        lg[tid] = ((a0 + a1) + (a2 + a3)) + (double)bias[tid];
    }
    __syncthreads();
    if (tid < T) {
        const double v = lg[tid];
        int rank = 0;
        for (int tp = 0; tp < T; ++tp) {
            double u = lg[tp];
            rank += (u > v) || (u == v && tp < tid);
        }
        if (rank < K) atomicOr(&flags[tid >> 5], 1u << (tid & 31));
    }
    __syncthreads();
    if (tid < T) {
        if ((flags[tid >> 5] >> (tid & 31)) & 1u) {
            int pos = __popc(flags[tid >> 5] & ((1u << (tid & 31)) - 1u));
            for (int u2 = 0; u2 < (tid >> 5); ++u2) pos += __popc(flags[u2]);
            sel[pos] = tid;
        }
    }
    __syncthreads();
    for (int k2 = wave; k2 < K; k2 += nw) {
        int t = sel[k2];
        const f4* src = (const f4*)(x + ((size_t)f * T + t) * D);
        f4*       dst = (f4*)(out + ((size_t)f * K + k2) * D);
        for (int p = lane; p < n4; p += 64)
            __builtin_nontemporal_store(src[p], &dst[p]);
    }
}

// ---------------------------------------------------------------------------
extern "C" void kernel_launch(void* const* d_in, const int* in_sizes, int n_in,
                              void* d_out, int out_size, void* d_ws, size_t ws_size,
                              hipStream_t stream) {
    const float* x     = (const float*)d_in[0];
    const float* pre_w = (const float*)d_in[1];
    const float* pre_b = (const float*)d_in[2];
    const float* W     = (const float*)d_in[3];
    const float* bias  = (const float*)d_in[4];
    float* outp = (float*)d_out;

    const int D = in_sizes[1];          // pre_w is [1, D]
    const int T = in_sizes[4];          // trans_bias is [T]
    const int F = in_sizes[0] / (T * D);
    const int K = out_size / (F * D);
    int NC = 4;

    double* s_glob = (double*)d_ws;

    bool ok = (F % NC == 0) && ((F / NC) * 4 <= 1024) && (T <= 576) &&
              (T % 4 == 0) && (K % 4 == 0) && ((T >> 2) % 16 == 0);
    if (ok) {
        dim3 grid((F / NC) * 4), block(1024);
        void* args[] = {(void*)&x, (void*)&pre_w, (void*)&pre_b, (void*)&W,
                        (void*)&bias, (void*)&outp, (void*)&s_glob,
                        (void*)&T, (void*)&D, (void*)&K, (void*)&F, (void*)&NC};
        hipError_t e = hipLaunchCooperativeKernel((void*)pipe_kernel, grid, block,
                                                  args, 0, stream);
        if (e == hipSuccess) return;
    }
    fused_select_kernel<<<F, 1024, 0, stream>>>(x, pre_w, pre_b, W, bias,
                                                outp, T, D, K);
}

// Round 4
// 263.082 us; speedup vs baseline: 4.5498x; 4.5498x over previous
//
#include <hip/hip_runtime.h>
#include <stdint.h>

typedef float f4 __attribute__((ext_vector_type(4)));

__device__ __forceinline__ double dot4d(f4 a, f4 b) {
    return (double)a.x * (double)b.x + (double)a.y * (double)b.y
         + (double)a.z * (double)b.z + (double)a.w * (double)b.w;
}

// ---------------------------------------------------------------------------
// One block per frame, 1024 threads (16 waves), compile-time shape.
// Phase 1: scores  — 8-lane group per token row, 4 independent f64 accs/lane,
//                    pre_w staged in LDS. Many loads in flight per wave.
// Phase 2: GEMV logits (f64, 8 accs) -> rank-select (value desc, index asc)
//          == stable top-K of argsort(-softmax); softmax monotonic -> skipped.
// Phase 3: bitmask+popcount compaction -> ascending token order.
// Phase 4: gather selected rows, 8-lane groups, nontemporal stores.
// ---------------------------------------------------------------------------
template <int T, int D, int K>
__global__ __launch_bounds__(1024)
void fused_opt_kernel(const float* __restrict__ x,
                      const float* __restrict__ pre_w,
                      const float* __restrict__ pre_b,
                      const float* __restrict__ W,
                      const float* __restrict__ bias,
                      float* __restrict__ out) {
    constexpr int N4 = D / 4;        // 352 float4 per row
    constexpr int NJ = N4 / 8;       // 44 iterations per 8-lane group
    constexpr int NG = 128;          // 8-lane groups per 1024-thread block
    constexpr int NW = (T + 31) / 32;

    __shared__ f4       w_sh[N4];
    __shared__ double   s_sh[T];
    __shared__ double   lg[T];
    __shared__ unsigned flags[NW];
    __shared__ int      sel[K];

    const int f   = blockIdx.x;
    const int tid = threadIdx.x;
    const int sub = tid & 7;         // lane position within 8-lane group
    const int gid = tid >> 3;        // group id 0..127

    for (int i = tid; i < N4; i += 1024) w_sh[i] = ((const f4*)pre_w)[i];
    if (tid < NW) flags[tid] = 0u;
    __syncthreads();

    // ---------------- Phase 1: per-token scores ----------------
    const double pb = (double)pre_b[0];
    for (int r = gid; r < T; r += NG) {
        const f4* xr = (const f4*)(x + ((size_t)f * T + r) * D);
        double a0 = 0, a1 = 0, a2 = 0, a3 = 0;
        #pragma unroll 2
        for (int j = 0; j < NJ; j += 4) {
            f4 v0 = xr[sub + 8 * (j + 0)];
            f4 v1 = xr[sub + 8 * (j + 1)];
            f4 v2 = xr[sub + 8 * (j + 2)];
            f4 v3 = xr[sub + 8 * (j + 3)];
            f4 u0 = w_sh[sub + 8 * (j + 0)];
            f4 u1 = w_sh[sub + 8 * (j + 1)];
            f4 u2 = w_sh[sub + 8 * (j + 2)];
            f4 u3 = w_sh[sub + 8 * (j + 3)];
            a0 += dot4d(v0, u0);
            a1 += dot4d(v1, u1);
            a2 += dot4d(v2, u2);
            a3 += dot4d(v3, u3);
        }
        double a = (a0 + a1) + (a2 + a3);
        a += __shfl_down(a, 4, 8);
        a += __shfl_down(a, 2, 8);
        a += __shfl_down(a, 1, 8);
        if (sub == 0) s_sh[r] = a + pb;
    }
    __syncthreads();

    // ---------------- Phase 2: GEMV logits + rank-select ----------------
    if (tid < T) {
        const float* Wc = W + tid;
        double acc[8] = {0, 0, 0, 0, 0, 0, 0, 0};
        for (int tp = 0; tp < T; tp += 8) {
            #pragma unroll
            for (int u = 0; u < 8; ++u)
                acc[u] += s_sh[tp + u] * (double)Wc[(size_t)(tp + u) * T];
        }
        double r01 = (acc[0] + acc[1]) + (acc[2] + acc[3]);
        double r23 = (acc[4] + acc[5]) + (acc[6] + acc[7]);
        lg[tid] = (r01 + r23) + (double)bias[tid];
    }
    __syncthreads();

    if (tid < T) {
        const double v = lg[tid];
        int rank = 0;
        #pragma unroll 8
        for (int tp = 0; tp < T; ++tp) {
            double u = lg[tp];
            rank += (u > v) || (u == v && tp < tid);
        }
        if (rank < K) atomicOr(&flags[tid >> 5], 1u << (tid & 31));
    }
    __syncthreads();

    // ---------------- Phase 3: ascending compaction ----------------
    if (tid < T) {
        if ((flags[tid >> 5] >> (tid & 31)) & 1u) {
            int pos = __popc(flags[tid >> 5] & ((1u << (tid & 31)) - 1u));
            for (int u2 = 0; u2 < (tid >> 5); ++u2) pos += __popc(flags[u2]);
            sel[pos] = tid;
        }
    }
    __syncthreads();

    // ---------------- Phase 4: gather selected rows ----------------
    for (int k2 = gid; k2 < K; k2 += NG) {
        const int t = sel[k2];
        const f4* src = (const f4*)(x + ((size_t)f * T + t) * D);
        f4*       dst = (f4*)(out + ((size_t)f * K + k2) * D);
        #pragma unroll 2
        for (int j = 0; j < NJ; j += 4) {
            f4 v0 = src[sub + 8 * (j + 0)];
            f4 v1 = src[sub + 8 * (j + 1)];
            f4 v2 = src[sub + 8 * (j + 2)];
            f4 v3 = src[sub + 8 * (j + 3)];
            __builtin_nontemporal_store(v0, &dst[sub + 8 * (j + 0)]);
            __builtin_nontemporal_store(v1, &dst[sub + 8 * (j + 1)]);
            __builtin_nontemporal_store(v2, &dst[sub + 8 * (j + 2)]);
            __builtin_nontemporal_store(v3, &dst[sub + 8 * (j + 3)]);
        }
    }
}

// ---------------------------------------------------------------------------
// Generic fallback (runtime shape) — proven-correct structure from R2/R3.
// ---------------------------------------------------------------------------
__global__ __launch_bounds__(1024)
void fused_select_kernel(const float* __restrict__ x,
                         const float* __restrict__ pre_w,
                         const float* __restrict__ pre_b,
                         const float* __restrict__ W,
                         const float* __restrict__ bias,
                         float* __restrict__ out,
                         int T, int D, int K) {
    __shared__ double   s_sh[1024];
    __shared__ double   lg[1024];
    __shared__ unsigned flags[32];
    __shared__ int      sel[576];

    const int f    = blockIdx.x;
    const int tid  = threadIdx.x;
    const int wave = tid >> 6;
    const int lane = tid & 63;
    const int nw   = blockDim.x >> 6;
    const int n4   = D >> 2;

    const f4* wv = (const f4*)pre_w;
    for (int t = wave; t < T; t += nw) {
        const f4* xr = (const f4*)(x + ((size_t)f * T + t) * D);
        double acc = 0.0;
        for (int p = lane; p < n4; p += 64) {
            f4 a = xr[p], c = wv[p];
            acc += dot4d(a, c);
        }
#pragma unroll
        for (int off = 32; off > 0; off >>= 1) acc += __shfl_down(acc, off);
        if (lane == 0) s_sh[t] = acc + (double)pre_b[0];
    }
    if (tid < 32) flags[tid] = 0u;
    __syncthreads();

    if (tid < T) {
        const float* Wc = W + tid;
        double a0 = 0, a1 = 0, a2 = 0, a3 = 0;
        int tp = 0;
        for (; tp + 4 <= T; tp += 4) {
            a0 += s_sh[tp + 0] * (double)Wc[(size_t)(tp + 0) * T];
            a1 += s_sh[tp + 1] * (double)Wc[(size_t)(tp + 1) * T];
            a2 += s_sh[tp + 2] * (double)Wc[(size_t)(tp + 2) * T];
            a3 += s_sh[tp + 3] * (double)Wc[(size_t)(tp + 3) * T];
        }
        for (; tp < T; ++tp) a0 += s_sh[tp] * (double)Wc[(size_t)tp * T];
        lg[tid] = ((a0 + a1) + (a2 + a3)) + (double)bias[tid];
    }
    __syncthreads();
    if (tid < T) {
        const double v = lg[tid];
        int rank = 0;
        for (int tp = 0; tp < T; ++tp) {
            double u = lg[tp];
            rank += (u > v) || (u == v && tp < tid);
        }
        if (rank < K) atomicOr(&flags[tid >> 5], 1u << (tid & 31));
    }
    __syncthreads();
    if (tid < T) {
        if ((flags[tid >> 5] >> (tid & 31)) & 1u) {
            int pos = __popc(flags[tid >> 5] & ((1u << (tid & 31)) - 1u));
            for (int u2 = 0; u2 < (tid >> 5); ++u2) pos += __popc(flags[u2]);
            sel[pos] = tid;
        }
    }
    __syncthreads();
    for (int k2 = wave; k2 < K; k2 += nw) {
        int t = sel[k2];
        const f4* src = (const f4*)(x + ((size_t)f * T + t) * D);
        f4*       dst = (f4*)(out + ((size_t)f * K + k2) * D);
        for (int p = lane; p < n4; p += 64)
            __builtin_nontemporal_store(src[p], &dst[p]);
    }
}

// ---------------------------------------------------------------------------
extern "C" void kernel_launch(void* const* d_in, const int* in_sizes, int n_in,
                              void* d_out, int out_size, void* d_ws, size_t ws_size,
                              hipStream_t stream) {
    const float* x     = (const float*)d_in[0];
    const float* pre_w = (const float*)d_in[1];
    const float* pre_b = (const float*)d_in[2];
    const float* W     = (const float*)d_in[3];
    const float* bias  = (const float*)d_in[4];
    float* outp = (float*)d_out;

    const int D = in_sizes[1];          // pre_w is [1, D]
    const int T = in_sizes[4];          // trans_bias is [T]
    const int F = in_sizes[0] / (T * D);
    const int K = out_size / (F * D);

    if (T == 576 && D == 1408 && K == 144) {
        fused_opt_kernel<576, 1408, 144><<<F, 1024, 0, stream>>>(
            x, pre_w, pre_b, W, bias, outp);
    } else {
        fused_select_kernel<<<F, 1024, 0, stream>>>(x, pre_w, pre_b, W, bias,
                                                    outp, T, D, K);
    }
}